// Round 8
// baseline (248.606 us; speedup 1.0000x reference)
//
#include <hip/hip_runtime.h>
#include <math.h>

typedef _Float16 half8  __attribute__((ext_vector_type(8)));
typedef _Float16 half4  __attribute__((ext_vector_type(4)));
typedef __fp16   fp16x2 __attribute__((ext_vector_type(2)));
typedef float    float4v __attribute__((ext_vector_type(4)));
typedef unsigned uint4v  __attribute__((ext_vector_type(4)));

#define NDIM   16
#define HID    128
#define NSTEP  10
#define RPW    2            // parents per WG; grid = 512 -> 2 WGs/CU
#define NROWS  48           // tile0: [x0,x1,xs0,xs1]x4 dup; tiles 1,2: tangents of p=0,1
#define XSTR   136          // hidden-activation row stride (halves)
#define SBS    17           // final-state row stride (fp32)

__device__ __forceinline__ float tanh_fast(float v) {
  // 1 - 2/(e^{2v}+1); rcp via v_rcp_f32 (1 trans inst, ~1e-6 rel err).
  float e = __expf(2.f * v);
  return 1.f - 2.f * __builtin_amdgcn_rcpf(e + 1.f);
}

// broadcast lane (4g+P) -> lanes 4g..4g+3 via DPP quad_perm (VALU pipe, no LDS)
template<int CTRL>
__device__ __forceinline__ float qbcast(float v) {
  int i = __builtin_amdgcn_update_dpp(0, __builtin_bit_cast(int, v), CTRL, 0xF, 0xF, true);
  return __builtin_bit_cast(float, i);
}

// packed f32->f16 conversion: v_cvt_pkrtz_f16_f32, 2 values per VALU inst
__device__ __forceinline__ unsigned pk2(float a, float b) {
  fp16x2 h = __builtin_amdgcn_cvt_pkrtz(a, b);
  return __builtin_bit_cast(unsigned, h);
}
__device__ __forceinline__ half8 h8pack(float a, float b, float c, float d,
                                        float e, float f, float g, float h) {
  uint4v u; u[0] = pk2(a,b); u[1] = pk2(c,d); u[2] = pk2(e,f); u[3] = pk2(g,h);
  return __builtin_bit_cast(half8, u);
}

// Permuted neuron storage: epilogue outputs (2 M-tiles x 4 C-rows) contiguous
// -> one ds_write_b128. Storage col c holds original neuron oneuron(c).
__device__ __forceinline__ int oneuron(int c) {
  return 32*(c >> 5) + 16*((c >> 2) & 1) + 4*((c >> 3) & 3) + (c & 3);
}

// STRUCTURE (r19 = r18 + t-column fix): r6 skeleton + L4/L0 PHASE MERGE via
// wave-replicated RK state. Phases are latency-bound (time ~ barrier count),
// so cut 201 -> 161: every wave computes Da = W4 h3 for ALL 3 tiles (12 MFMA)
// and replicates the full RK state (sbr/sar[3][4], +16 regs). The next
// stage's layer-0 B-frag is built IN REGISTERS: pk2 the updated z,
// ds_bpermute the (z-dim x col) transpose (no barrier), 6 A0 MFMAs + finish
// in the SAME phase. XI and the standalone L0 phase are gone: 4 phases/stage.
// r18 bug: t in the k=16 slot was applied to ALL tiles; tangent tiles must
// get 0 there (tangent propagation uses J_z only) -> absmax 0.615. Fixed:
// tn only for nt==0.
__global__ __launch_bounds__(256, 2)
void flow_ode_kernel(const float* __restrict__ gx,  const float* __restrict__ gxs,
                     const float* __restrict__ W0,  const float* __restrict__ b0,
                     const float* __restrict__ W1,  const float* __restrict__ b1,
                     const float* __restrict__ W2,  const float* __restrict__ b2,
                     const float* __restrict__ W3,  const float* __restrict__ b3,
                     const float* __restrict__ W4,  const float* __restrict__ b4,
                     float* __restrict__ out)
{
  __shared__ __align__(16) _Float16 XT[2][NROWS][XSTR];  // hidden activations ping-pong
  __shared__ float SbL[NROWS][SBS];                      // final state (solve only)

  const int tid  = threadIdx.x;
  const int mi   = tid >> 6;
  const int lane = tid & 63;
  const int q    = lane >> 4;
  const int ln   = lane & 15;
  const int g0   = blockIdx.x * RPW;

  // ---------------- weight fragments (permuted storage order) ----------------
  half8 A0[2];
  half8 A1[2][4], A2[2][4], A3[2][4];
  half8 A4[4];
  float bw[4][2][4];
  float b4r[4];

  #pragma unroll
  for (int mt = 0; mt < 2; ++mt) {
    const int m = 16*(2*mi + mt) + ln;       // original out-neuron for A-row ln
    #pragma unroll
    for (int j = 0; j < 8; ++j) {
      const int k = 8*q + j;                 // z dims 0..15 + t at k=16
      A0[mt][j] = (k < NDIM+1) ? (_Float16)W0[k*HID + m] : (_Float16)0.f;
    }
    #pragma unroll
    for (int ks = 0; ks < 4; ++ks) {
      #pragma unroll
      for (int j = 0; j < 8; ++j) {
        const int k = oneuron(32*ks + 8*q + j);   // storage col -> original neuron
        A1[mt][ks][j] = (_Float16)W1[k*HID + m];
        A2[mt][ks][j] = (_Float16)W2[k*HID + m];
        A3[mt][ks][j] = (_Float16)W3[k*HID + m];
      }
    }
  }
  #pragma unroll
  for (int ks = 0; ks < 4; ++ks)
    #pragma unroll
    for (int j = 0; j < 8; ++j)
      A4[ks][j] = (_Float16)W4[oneuron(32*ks + 8*q + j)*NDIM + ln];

  #pragma unroll
  for (int mt = 0; mt < 2; ++mt)
    #pragma unroll
    for (int r = 0; r < 4; ++r) {
      const int m = 16*(2*mi + mt) + 4*q + r;
      bw[0][mt][r] = b0[m];
      bw[1][mt][r] = b1[m];
      bw[2][mt][r] = b2[m];
      bw[3][mt][r] = b3[m];
    }
  #pragma unroll
  for (int r = 0; r < 4; ++r) b4r[r] = b4[4*q + r];

  // ---------------- RK state, replicated in ALL waves, ALL tiles ----------------
  // lane (q,ln): tile nt, column ln, dims 4q+r.
  float sbr[3][4], sar[3][4];
  {
    const int p = ln & 3;                                // [x0,x1,xs0,xs1] pattern
    const float* src = (p < 2) ? (gx + (g0 + p)*NDIM) : (gxs + (g0 + p - 2)*NDIM);
    #pragma unroll
    for (int r = 0; r < 4; ++r) {
      sbr[0][r] = src[4*q + r];
      const float e = (ln == 4*q + r) ? 1.f : 0.f;       // tangent e_ln
      sbr[1][r] = e;
      sbr[2][r] = e;
      sar[0][r] = 0.f; sar[1][r] = 0.f; sar[2][r] = 0.f;
    }
  }

  const float dt = 1.f / NSTEP;

  // epilogue: tile0 -> tanh (bias pre-folded in C-init); tiles 1,2 -> scale by
  // quad_perm-broadcast (1-h^2) of the parent. One b128 write per N-tile.
  auto finish = [&](float4v (&D)[2][3], int wb) {
    float hs[2][4], ss[2][4];
    #pragma unroll
    for (int mt = 0; mt < 2; ++mt)
      #pragma unroll
      for (int r = 0; r < 4; ++r) {
        const float h = tanh_fast(D[mt][0][r]);
        hs[mt][r] = h;
        ss[mt][r] = 1.f - h*h;
      }
    *(half8*)&XT[wb][ln][32*mi + 8*q] =
        h8pack(hs[0][0], hs[0][1], hs[0][2], hs[0][3],
               hs[1][0], hs[1][1], hs[1][2], hs[1][3]);
    float t1v[2][4], t2v[2][4];
    #pragma unroll
    for (int mt = 0; mt < 2; ++mt)
      #pragma unroll
      for (int r = 0; r < 4; ++r) {
        t1v[mt][r] = D[mt][1][r] * qbcast<0x00>(ss[mt][r]);   // parent 0
        t2v[mt][r] = D[mt][2][r] * qbcast<0x55>(ss[mt][r]);   // parent 1
      }
    *(half8*)&XT[wb][16 + ln][32*mi + 8*q] =
        h8pack(t1v[0][0], t1v[0][1], t1v[0][2], t1v[0][3],
               t1v[1][0], t1v[1][1], t1v[1][2], t1v[1][3]);
    *(half8*)&XT[wb][32 + ln][32*mi + 8*q] =
        h8pack(t2v[0][0], t2v[0][1], t2v[0][2], t2v[0][3],
               t2v[1][0], t2v[1][1], t2v[1][2], t2v[1][3]);
    __syncthreads();
  };

  auto mid_layer = [&](const half8 (&A)[2][4], const float (&bb)[2][4], int rb, int wb) {
    float4v D[2][3];
    #pragma unroll
    for (int mt = 0; mt < 2; ++mt)
      #pragma unroll
      for (int nt = 0; nt < 3; ++nt)
        #pragma unroll
        for (int e = 0; e < 4; ++e) D[mt][nt][e] = (nt == 0) ? bb[mt][e] : 0.f;
    #pragma unroll
    for (int ks = 0; ks < 4; ++ks) {
      half8 Bf[3];
      #pragma unroll
      for (int nt = 0; nt < 3; ++nt)
        Bf[nt] = *(const half8*)&XT[rb][nt*16 + ln][32*ks + 8*q];
      #pragma unroll
      for (int nt = 0; nt < 3; ++nt) {
        D[0][nt] = __builtin_amdgcn_mfma_f32_16x16x32_f16(A[0][ks], Bf[nt], D[0][nt], 0, 0, 0);
        D[1][nt] = __builtin_amdgcn_mfma_f32_16x16x32_f16(A[1][ks], Bf[nt], D[1][nt], 0, 0, 0);
      }
    }
    finish(D, wb);
  };

  // layer-0 from registers: build B-frags from per-lane z (dims 4q+r, col ln)
  // via pk2 + ds_bpermute transpose; then 6 A0 MFMAs + finish -> XT[0].
  // t rides in k=16 (q==2, j==0) for the STATE tile only; tangents get 0.
  auto l0_from_regs = [&](float (&xn)[3][4], float tn) {
    // dest lane (q,ln) needs dims 8q+j of col ln: j=0..3 from lane 32q+ln,
    // j=4..7 from lane 32q+16+ln (q<2; q==2 carries t for nt=0, q==3 zero).
    const int s0 = ((lane & 48) << 1) + (lane & 15);
    uint4v bfu[3];
    #pragma unroll
    for (int nt = 0; nt < 3; ++nt) {
      const int lo = (int)pk2(xn[nt][0], xn[nt][1]);
      const int hi = (int)pk2(xn[nt][2], xn[nt][3]);
      unsigned u0 = (unsigned)__builtin_amdgcn_ds_bpermute(s0 << 2, lo);
      unsigned u1 = (unsigned)__builtin_amdgcn_ds_bpermute(s0 << 2, hi);
      unsigned u2 = (unsigned)__builtin_amdgcn_ds_bpermute((s0 + 16) << 2, lo);
      unsigned u3 = (unsigned)__builtin_amdgcn_ds_bpermute((s0 + 16) << 2, hi);
      if (q == 2) { u0 = (nt == 0) ? pk2(tn, 0.f) : 0u; u1 = 0u; u2 = 0u; u3 = 0u; }
      if (q == 3) { u0 = 0u; u1 = 0u; u2 = 0u; u3 = 0u; }
      bfu[nt][0] = u0; bfu[nt][1] = u1; bfu[nt][2] = u2; bfu[nt][3] = u3;
    }
    float4v D[2][3];
    #pragma unroll
    for (int mt = 0; mt < 2; ++mt)
      #pragma unroll
      for (int nt = 0; nt < 3; ++nt)
        #pragma unroll
        for (int e = 0; e < 4; ++e) D[mt][nt][e] = (nt == 0) ? bw[0][mt][e] : 0.f;
    #pragma unroll
    for (int nt = 0; nt < 3; ++nt) {
      half8 Bf = __builtin_bit_cast(half8, bfu[nt]);
      D[0][nt] = __builtin_amdgcn_mfma_f32_16x16x32_f16(A0[0], Bf, D[0][nt], 0, 0, 0);
      D[1][nt] = __builtin_amdgcn_mfma_f32_16x16x32_f16(A0[1], Bf, D[1][nt], 0, 0, 0);
    }
    finish(D, 0);
  };

  // ---------------- init: h0(z0, t=0) straight from registers ----------------
  {
    float xn0[3][4];
    #pragma unroll
    for (int nt = 0; nt < 3; ++nt)
      #pragma unroll
      for (int r = 0; r < 4; ++r) xn0[nt][r] = sbr[nt][r];
    l0_from_regs(xn0, 0.f);
  }

  // phase-offset odd WGs so the two co-resident barrier domains interleave
  // LDS-port bursts instead of phase-locking.
  if (blockIdx.x & 1) __builtin_amdgcn_s_sleep(22);

  // ---------------- 10 RK4 steps x 4 stages x 4 phases ----------------
  #pragma unroll 1
  for (int step = 0; step < NSTEP; ++step) {
    const float t0 = step * dt;
    #pragma unroll
    for (int stage = 0; stage < 4; ++stage) {
      mid_layer(A1, bw[1], 0, 1);
      mid_layer(A2, bw[2], 1, 0);
      mid_layer(A3, bw[3], 0, 1);
      { // ---- merged: L4 (all tiles, all waves) + RK + next-stage L0 ----
        float4v Da[3];
        #pragma unroll
        for (int nt = 0; nt < 3; ++nt)
          #pragma unroll
          for (int e = 0; e < 4; ++e) Da[nt][e] = (nt == 0) ? b4r[e] : 0.f;
        #pragma unroll
        for (int ks = 0; ks < 4; ++ks) {
          #pragma unroll
          for (int nt = 0; nt < 3; ++nt) {
            half8 Ba = *(const half8*)&XT[1][nt*16 + ln][32*ks + 8*q];
            Da[nt] = __builtin_amdgcn_mfma_f32_16x16x32_f16(A4[ks], Ba, Da[nt], 0, 0, 0);
          }
        }
        const float c_s = (stage < 2) ? 0.5f*dt : dt;
        const float tn  = t0 + c_s;          // stage 3: next step's t0
        float xn[3][4];
        if (stage < 3) {
          const float w_s = (stage == 0) ? 1.f : 2.f;
          #pragma unroll
          for (int nt = 0; nt < 3; ++nt)
            #pragma unroll
            for (int r = 0; r < 4; ++r) {
              sar[nt][r] += w_s * Da[nt][r];
              xn[nt][r] = sbr[nt][r] + c_s * Da[nt][r];
            }
        } else {
          #pragma unroll
          for (int nt = 0; nt < 3; ++nt)
            #pragma unroll
            for (int r = 0; r < 4; ++r) {
              sbr[nt][r] += (dt * (1.f/6.f)) * (sar[nt][r] + Da[nt][r]);
              sar[nt][r] = 0.f;
              xn[nt][r] = sbr[nt][r];
            }
        }
        l0_from_regs(xn, tn);
      }
    }
  }

  // ---------------- dump state (wave 0 has everything), then solve ----------------
  if (mi == 0) {
    #pragma unroll
    for (int nt = 0; nt < 3; ++nt)
      #pragma unroll
      for (int r = 0; r < 4; ++r)
        SbL[nt*16 + ln][4*q + r] = sbr[nt][r];
  }
  __syncthreads();

  if (mi < RPW) {
    const int p    = mi;
    const int jj   = ln;
    const int base = lane & 48;
    float c[NDIM], gv[NDIM], G[NDIM];
    #pragma unroll
    for (int i = 0; i < NDIM; ++i) c[i] = SbL[16 + 16*p + jj][i];   // J[:, jj]
    float n2 = 0.f;
    #pragma unroll
    for (int i = 0; i < NDIM; ++i) {
      gv[i] = SbL[p][i] - SbL[2 + p][i];                            // y - y*
      n2 += gv[i]*gv[i];
    }
    const float rinv = 1.f / (sqrtf(n2) + 1e-8f);
    float rhs = 0.f;
    #pragma unroll
    for (int i = 0; i < NDIM; ++i) rhs += c[i] * gv[i];
    rhs *= rinv;
    #pragma unroll
    for (int k = 0; k < NDIM; ++k) {
      float acc = (k == jj) ? 1e-6f : 0.f;
      #pragma unroll
      for (int i = 0; i < NDIM; ++i)
        acc += c[i] * __shfl(c[i], base + k, 64);
      G[k] = acc;
    }
    #pragma unroll
    for (int k = 0; k < NDIM-1; ++k) {
      const float piv  = __shfl(G[k], base + k, 64);
      const float prhs = __shfl(rhs,  base + k, 64);
      const float f = (jj > k) ? G[k] / piv : 0.f;
      #pragma unroll
      for (int cc = k; cc < NDIM; ++cc)
        G[cc] -= f * __shfl(G[cc], base + k, 64);
      rhs -= f * prhs;
    }
    float sol = 0.f;
    #pragma unroll
    for (int k = NDIM-1; k >= 0; --k) {
      const float piv = __shfl(G[k], base + k, 64);
      const float pr  = __shfl(rhs,  base + k, 64);
      const float xk  = pr / piv;
      if (jj == k) sol = xk;
      if (jj <  k) rhs -= G[k] * xk;
    }
    if (lane < NDIM)
      out[(g0 + p)*NDIM + jj] = -sol;
  }
}

extern "C" void kernel_launch(void* const* d_in, const int* in_sizes, int n_in,
                              void* d_out, int out_size, void* d_ws, size_t ws_size,
                              hipStream_t stream) {
  (void)in_sizes; (void)n_in; (void)d_ws; (void)ws_size; (void)out_size;
  flow_ode_kernel<<<dim3(512), dim3(256), 0, stream>>>(
      (const float*)d_in[0],  (const float*)d_in[1],
      (const float*)d_in[2],  (const float*)d_in[3],
      (const float*)d_in[4],  (const float*)d_in[5],
      (const float*)d_in[6],  (const float*)d_in[7],
      (const float*)d_in[8],  (const float*)d_in[9],
      (const float*)d_in[10], (const float*)d_in[11],
      (float*)d_out);
}

// Round 9
// 213.000 us; speedup vs baseline: 1.1672x; 1.1672x over previous
//
#include <hip/hip_runtime.h>
#include <math.h>

typedef _Float16 half8  __attribute__((ext_vector_type(8)));
typedef _Float16 half4  __attribute__((ext_vector_type(4)));
typedef __fp16   fp16x2 __attribute__((ext_vector_type(2)));
typedef float    float4v __attribute__((ext_vector_type(4)));
typedef unsigned uint4v  __attribute__((ext_vector_type(4)));
typedef unsigned uint2v  __attribute__((ext_vector_type(2)));

#define NDIM   16
#define HID    128
#define NSTEP  10
#define RPW    2            // parents per WG; grid = 512 -> 2 WGs/CU
#define NROWS  48           // tile0: [x0,x1,xs0,xs1]x4 dup; tiles 1,2: tangents of p=0,1
#define XSTR   136          // hidden-activation row stride (halves)
#define XISTR  40           // layer-0 input row stride (halves)
#define SBS    17           // final-state row stride (fp32)

__device__ __forceinline__ float tanh_fast(float v) {
  // 1 - 2/(e^{2v}+1); rcp via v_rcp_f32 (1 trans inst, ~1e-6 rel err).
  float e = __expf(2.f * v);
  return 1.f - 2.f * __builtin_amdgcn_rcpf(e + 1.f);
}

// broadcast lane (4g+P) -> lanes 4g..4g+3 via DPP quad_perm (VALU pipe, no LDS)
template<int CTRL>
__device__ __forceinline__ float qbcast(float v) {
  int i = __builtin_amdgcn_update_dpp(0, __builtin_bit_cast(int, v), CTRL, 0xF, 0xF, true);
  return __builtin_bit_cast(float, i);
}

// packed f32->f16 conversion: v_cvt_pkrtz_f16_f32, 2 values per VALU inst
__device__ __forceinline__ unsigned pk2(float a, float b) {
  fp16x2 h = __builtin_amdgcn_cvt_pkrtz(a, b);
  return __builtin_bit_cast(unsigned, h);
}
__device__ __forceinline__ half8 h8pack(float a, float b, float c, float d,
                                        float e, float f, float g, float h) {
  uint4v u; u[0] = pk2(a,b); u[1] = pk2(c,d); u[2] = pk2(e,f); u[3] = pk2(g,h);
  return __builtin_bit_cast(half8, u);
}
__device__ __forceinline__ half4 h4pack(float a, float b, float c, float d) {
  uint2v u; u[0] = pk2(a,b); u[1] = pk2(c,d);
  return __builtin_bit_cast(half4, u);
}

// Permuted neuron storage: epilogue outputs (2 M-tiles x 4 C-rows) contiguous
// -> one ds_write_b128. Storage col c holds original neuron oneuron(c).
__device__ __forceinline__ int oneuron(int c) {
  return 32*(c >> 5) + 16*((c >> 2) & 1) + 4*((c >> 3) & 3) + (c & 3);
}

// STRUCTURE (r20): exact r6 skeleton (the measured floor of the family:
// r12 more-waves spilled, r13 dual-pipeline ILP lost, r14 preact fusion
// spilled, r16 swizzle wrong-math, r18/r19 L4-L0 merge regressed 180->209 --
// the merged serial chain cost more than the saved barrier) + s_setprio(1)
// around the MFMA clusters. Mechanism: the two co-resident WGs are
// phase-offset (~half layer period, s_sleep below), so at any time one WG's
// waves are MFMA-issuing while the other's are in LDS/VALU epilogue --
// priority biases the SIMD arbiter toward the matrix pipe during the burst
// (same role-split property that gave +4-7% in attn; null when lockstep).
__global__ __launch_bounds__(256, 2)
void flow_ode_kernel(const float* __restrict__ gx,  const float* __restrict__ gxs,
                     const float* __restrict__ W0,  const float* __restrict__ b0,
                     const float* __restrict__ W1,  const float* __restrict__ b1,
                     const float* __restrict__ W2,  const float* __restrict__ b2,
                     const float* __restrict__ W3,  const float* __restrict__ b3,
                     const float* __restrict__ W4,  const float* __restrict__ b4,
                     float* __restrict__ out)
{
  __shared__ __align__(16) _Float16 XT[2][NROWS][XSTR];  // hidden activations ping-pong
  __shared__ __align__(16) _Float16 XI[NROWS][XISTR];    // layer-0 input
  __shared__ float SbL[NROWS][SBS];                      // final state (solve only)

  const int tid  = threadIdx.x;
  const int mi   = tid >> 6;
  const int lane = tid & 63;
  const int q    = lane >> 4;
  const int ln   = lane & 15;
  const int g0   = blockIdx.x * RPW;

  // ---------------- weight fragments (permuted storage order) ----------------
  half8 A0[2];
  half8 A1[2][4], A2[2][4], A3[2][4];
  half8 A4[4];
  float bw[4][2][4];
  float b4r[4];

  #pragma unroll
  for (int mt = 0; mt < 2; ++mt) {
    const int m = 16*(2*mi + mt) + ln;       // original out-neuron for A-row ln
    #pragma unroll
    for (int j = 0; j < 8; ++j) {
      const int k = 8*q + j;                 // XI cols are unpermuted
      A0[mt][j] = (k < NDIM+1) ? (_Float16)W0[k*HID + m] : (_Float16)0.f;
    }
    #pragma unroll
    for (int ks = 0; ks < 4; ++ks) {
      #pragma unroll
      for (int j = 0; j < 8; ++j) {
        const int k = oneuron(32*ks + 8*q + j);   // storage col -> original neuron
        A1[mt][ks][j] = (_Float16)W1[k*HID + m];
        A2[mt][ks][j] = (_Float16)W2[k*HID + m];
        A3[mt][ks][j] = (_Float16)W3[k*HID + m];
      }
    }
  }
  #pragma unroll
  for (int ks = 0; ks < 4; ++ks)
    #pragma unroll
    for (int j = 0; j < 8; ++j)
      A4[ks][j] = (_Float16)W4[oneuron(32*ks + 8*q + j)*NDIM + ln];

  #pragma unroll
  for (int mt = 0; mt < 2; ++mt)
    #pragma unroll
    for (int r = 0; r < 4; ++r) {
      const int m = 16*(2*mi + mt) + 4*q + r;
      bw[0][mt][r] = b0[m];
      bw[1][mt][r] = b1[m];
      bw[2][mt][r] = b2[m];
      bw[3][mt][r] = b3[m];
    }
  #pragma unroll
  for (int r = 0; r < 4; ++r) b4r[r] = b4[4*q + r];

  // ---------------- RK state in registers ----------------
  // wave mi (<3) owns tile mi; lane (q,ln): row ln, dims 4q+r.
  float sbr[4], sar[4];
  if (mi == 0) {
    const int p = ln & 3;                                // [x0,x1,xs0,xs1] pattern
    const float* src = (p < 2) ? (gx + (g0 + p)*NDIM) : (gxs + (g0 + p - 2)*NDIM);
    #pragma unroll
    for (int r = 0; r < 4; ++r) sbr[r] = src[4*q + r];
  } else {
    #pragma unroll
    for (int r = 0; r < 4; ++r) sbr[r] = (ln == 4*q + r) ? 1.f : 0.f;  // tangent e_ln
  }
  #pragma unroll
  for (int r = 0; r < 4; ++r) sar[r] = 0.f;

  // ---------------- init XI (cols 0..31; 16..31 zeroed once, t(=0) included) ----------------
  for (int idx = tid; idx < NROWS*32; idx += 256)
    XI[idx >> 5][idx & 31] = (_Float16)0.f;
  __syncthreads();
  if (mi < 3) {
    half4 x4;
    #pragma unroll
    for (int r = 0; r < 4; ++r) x4[r] = (_Float16)sbr[r];
    *(half4*)&XI[mi*16 + ln][4*q] = x4;
  }
  __syncthreads();

  // phase-offset odd WGs by ~half a layer period so the two co-resident
  // barrier domains interleave LDS-port bursts instead of phase-locking.
  if (blockIdx.x & 1) __builtin_amdgcn_s_sleep(22);

  const float dt = 1.f / NSTEP;

  // epilogue: tile0 -> tanh (bias pre-folded in C-init); tiles 1,2 -> scale by
  // quad_perm-broadcast (1-h^2) of the parent. One b128 write per N-tile.
  auto finish = [&](float4v (&D)[2][3], int wb) {
    float hs[2][4], ss[2][4];
    #pragma unroll
    for (int mt = 0; mt < 2; ++mt)
      #pragma unroll
      for (int r = 0; r < 4; ++r) {
        const float h = tanh_fast(D[mt][0][r]);
        hs[mt][r] = h;
        ss[mt][r] = 1.f - h*h;
      }
    *(half8*)&XT[wb][ln][32*mi + 8*q] =
        h8pack(hs[0][0], hs[0][1], hs[0][2], hs[0][3],
               hs[1][0], hs[1][1], hs[1][2], hs[1][3]);
    float t1v[2][4], t2v[2][4];
    #pragma unroll
    for (int mt = 0; mt < 2; ++mt)
      #pragma unroll
      for (int r = 0; r < 4; ++r) {
        t1v[mt][r] = D[mt][1][r] * qbcast<0x00>(ss[mt][r]);   // parent 0
        t2v[mt][r] = D[mt][2][r] * qbcast<0x55>(ss[mt][r]);   // parent 1
      }
    *(half8*)&XT[wb][16 + ln][32*mi + 8*q] =
        h8pack(t1v[0][0], t1v[0][1], t1v[0][2], t1v[0][3],
               t1v[1][0], t1v[1][1], t1v[1][2], t1v[1][3]);
    *(half8*)&XT[wb][32 + ln][32*mi + 8*q] =
        h8pack(t2v[0][0], t2v[0][1], t2v[0][2], t2v[0][3],
               t2v[1][0], t2v[1][1], t2v[1][2], t2v[1][3]);
    __syncthreads();
  };

  auto mid_layer = [&](const half8 (&A)[2][4], const float (&bb)[2][4], int rb, int wb) {
    float4v D[2][3];
    #pragma unroll
    for (int mt = 0; mt < 2; ++mt)
      #pragma unroll
      for (int nt = 0; nt < 3; ++nt)
        #pragma unroll
        for (int e = 0; e < 4; ++e) D[mt][nt][e] = (nt == 0) ? bb[mt][e] : 0.f;
    __builtin_amdgcn_s_setprio(1);
    #pragma unroll
    for (int ks = 0; ks < 4; ++ks) {
      half8 Bf[3];
      #pragma unroll
      for (int nt = 0; nt < 3; ++nt)
        Bf[nt] = *(const half8*)&XT[rb][nt*16 + ln][32*ks + 8*q];
      #pragma unroll
      for (int nt = 0; nt < 3; ++nt) {
        D[0][nt] = __builtin_amdgcn_mfma_f32_16x16x32_f16(A[0][ks], Bf[nt], D[0][nt], 0, 0, 0);
        D[1][nt] = __builtin_amdgcn_mfma_f32_16x16x32_f16(A[1][ks], Bf[nt], D[1][nt], 0, 0, 0);
      }
    }
    __builtin_amdgcn_s_setprio(0);
    finish(D, wb);
  };

  // ---------------- 10 RK4 steps x 4 stages (stage loop fully unrolled) ----------------
  #pragma unroll 1
  for (int step = 0; step < NSTEP; ++step) {
    const float t0 = step * dt;
    #pragma unroll
    for (int stage = 0; stage < 4; ++stage) {
      { // ---- layer 0 (K = 32 from XI) -> XT[0] ----
        float4v D[2][3];
        #pragma unroll
        for (int mt = 0; mt < 2; ++mt)
          #pragma unroll
          for (int nt = 0; nt < 3; ++nt)
            #pragma unroll
            for (int e = 0; e < 4; ++e) D[mt][nt][e] = (nt == 0) ? bw[0][mt][e] : 0.f;
        half8 Bf[3];
        #pragma unroll
        for (int nt = 0; nt < 3; ++nt)
          Bf[nt] = *(const half8*)&XI[nt*16 + ln][8*q];
        __builtin_amdgcn_s_setprio(1);
        #pragma unroll
        for (int nt = 0; nt < 3; ++nt) {
          D[0][nt] = __builtin_amdgcn_mfma_f32_16x16x32_f16(A0[0], Bf[nt], D[0][nt], 0, 0, 0);
          D[1][nt] = __builtin_amdgcn_mfma_f32_16x16x32_f16(A0[1], Bf[nt], D[1][nt], 0, 0, 0);
        }
        __builtin_amdgcn_s_setprio(0);
        finish(D, 0);
      }
      mid_layer(A1, bw[1], 0, 1);
      mid_layer(A2, bw[2], 1, 0);
      mid_layer(A3, bw[3], 0, 1);
      { // ---- layer 4 (reads XT[1]) + RK update: waves 0..2 own tiles 0..2 ----
        if (mi < 3) {
          float4v Da;
          #pragma unroll
          for (int e = 0; e < 4; ++e) Da[e] = (mi == 0) ? b4r[e] : 0.f;
          __builtin_amdgcn_s_setprio(1);
          #pragma unroll
          for (int ks = 0; ks < 4; ++ks) {
            half8 Ba = *(const half8*)&XT[1][mi*16 + ln][32*ks + 8*q];
            Da = __builtin_amdgcn_mfma_f32_16x16x32_f16(A4[ks], Ba, Da, 0, 0, 0);
          }
          __builtin_amdgcn_s_setprio(0);
          const float c_s = (stage < 2) ? 0.5f*dt : dt;
          half4 xn;
          if (stage < 3) {
            const float w_s = (stage == 0) ? 1.f : 2.f;
            float xv[4];
            #pragma unroll
            for (int r = 0; r < 4; ++r) {
              sar[r] += w_s * Da[r];
              xv[r] = sbr[r] + c_s * Da[r];
            }
            xn = h4pack(xv[0], xv[1], xv[2], xv[3]);
          } else {
            float xv[4];
            #pragma unroll
            for (int r = 0; r < 4; ++r) {
              const float nb = sbr[r] + (dt * (1.f/6.f)) * (sar[r] + Da[r]);
              sbr[r] = nb;
              sar[r] = 0.f;
              xv[r] = nb;
            }
            xn = h4pack(xv[0], xv[1], xv[2], xv[3]);
          }
          *(half4*)&XI[mi*16 + ln][4*q] = xn;
          if (mi == 0 && q == 0)
            XI[ln][16] = (_Float16)(t0 + ((stage < 2) ? 0.5f*dt : dt));  // t column
        }
        __syncthreads();
      }
    }
  }

  // ---------------- dump state, then per-parent solve ----------------
  if (mi < 3) {
    #pragma unroll
    for (int r = 0; r < 4; ++r)
      SbL[mi*16 + ln][4*q + r] = sbr[r];
  }
  __syncthreads();

  if (mi < RPW) {
    const int p    = mi;
    const int jj   = ln;
    const int base = lane & 48;
    float c[NDIM], gv[NDIM], G[NDIM];
    #pragma unroll
    for (int i = 0; i < NDIM; ++i) c[i] = SbL[16 + 16*p + jj][i];   // J[:, jj]
    float n2 = 0.f;
    #pragma unroll
    for (int i = 0; i < NDIM; ++i) {
      // tile0 col layout [x0,x1,xs0,xs1]x4: x_p at col p, xs_p at col 2+p
      gv[i] = SbL[p][i] - SbL[2 + p][i];                            // y - y*
      n2 += gv[i]*gv[i];
    }
    const float rinv = 1.f / (sqrtf(n2) + 1e-8f);
    float rhs = 0.f;
    #pragma unroll
    for (int i = 0; i < NDIM; ++i) rhs += c[i] * gv[i];
    rhs *= rinv;
    #pragma unroll
    for (int k = 0; k < NDIM; ++k) {
      float acc = (k == jj) ? 1e-6f : 0.f;
      #pragma unroll
      for (int i = 0; i < NDIM; ++i)
        acc += c[i] * __shfl(c[i], base + k, 64);
      G[k] = acc;
    }
    #pragma unroll
    for (int k = 0; k < NDIM-1; ++k) {
      const float piv  = __shfl(G[k], base + k, 64);
      const float prhs = __shfl(rhs,  base + k, 64);
      const float f = (jj > k) ? G[k] / piv : 0.f;
      #pragma unroll
      for (int cc = k; cc < NDIM; ++cc)
        G[cc] -= f * __shfl(G[cc], base + k, 64);
      rhs -= f * prhs;
    }
    float sol = 0.f;
    #pragma unroll
    for (int k = NDIM-1; k >= 0; --k) {
      const float piv = __shfl(G[k], base + k, 64);
      const float pr  = __shfl(rhs,  base + k, 64);
      const float xk  = pr / piv;
      if (jj == k) sol = xk;
      if (jj <  k) rhs -= G[k] * xk;
    }
    if (lane < NDIM)
      out[(g0 + p)*NDIM + jj] = -sol;
  }
}

extern "C" void kernel_launch(void* const* d_in, const int* in_sizes, int n_in,
                              void* d_out, int out_size, void* d_ws, size_t ws_size,
                              hipStream_t stream) {
  (void)in_sizes; (void)n_in; (void)d_ws; (void)ws_size; (void)out_size;
  flow_ode_kernel<<<dim3(512), dim3(256), 0, stream>>>(
      (const float*)d_in[0],  (const float*)d_in[1],
      (const float*)d_in[2],  (const float*)d_in[3],
      (const float*)d_in[4],  (const float*)d_in[5],
      (const float*)d_in[6],  (const float*)d_in[7],
      (const float*)d_in[8],  (const float*)d_in[9],
      (const float*)d_in[10], (const float*)d_in[11],
      (float*)d_out);
}